// Round 1
// baseline (569.495 us; speedup 1.0000x reference)
//
#include <hip/hip_runtime.h>

// Problem constants (from reference)
#define VOCAB   20000
#define GLOVE   300
#define C4      75            // GLOVE/4 float4 groups per 300-col row
#define RTOT    16            // 2*TOP_K rows of 300 per vocab entry
#define OUTC    100
#define NLAB    8
#define NOUT    4096          // B*L
#define FT_ROW  (RTOT * GLOVE)   // 4800 floats per vocab entry
#define ROWS_A  16            // vocab rows per block in reduce kernel
#define NITEM   (ROWS_A * C4) // 1200 work items per block

// ---------------------------------------------------------------------------
// K1: scatter flags — mark which vocab rows are referenced by any label.
// Races (multiple writers of 1) are benign.
// ---------------------------------------------------------------------------
__global__ __launch_bounds__(256) void k_flags(const int* __restrict__ labels,
                                               int* __restrict__ flags, int n) {
    int i = blockIdx.x * 256 + threadIdx.x;
    if (i < n) flags[labels[i]] = 1;
}

// ---------------------------------------------------------------------------
// K2 (the big one): for each touched vocab row v:
//   rowsum[c] = sum_{r<16} ft[v][r*300 + c]          (phase 1, LDS)
//   proj[v][o] = sum_c rowsum[c] * W[o][c]           (phase 2)
// Block = 256 threads, handles 16 vocab rows. LDS = 16*300*4 = 19.2 KB
// -> 8 blocks/CU (LDS- and wave-capped), good memory parallelism.
// Phase 2: wave w owns rows r0=4w..4w+3; lane -> output o (o and o+64),
// rowsum read via wave-uniform float4 LDS broadcast (1 instr / 64 lanes).
// ---------------------------------------------------------------------------
__global__ __launch_bounds__(256) void k_reduce_proj(const float* __restrict__ ft,
                                                     const float* __restrict__ W,
                                                     const int* __restrict__ flags,
                                                     float* __restrict__ proj) {
    __shared__ float lds[ROWS_A * GLOVE];
    const int vbase = blockIdx.x * ROWS_A;
    const int tid = threadIdx.x;

    // ---- phase 1: global -> LDS rowsum, coalesced float4, flag-skipped ----
    for (int i = tid; i < NITEM; i += 256) {
        const int r  = i / C4;         // local vocab row 0..15
        const int cg = i - r * C4;     // float4 column group 0..74
        const int v  = vbase + r;
        float sx = 0.f, sy = 0.f, sz = 0.f, sw = 0.f;
        if (flags[v]) {
            const float4* p = reinterpret_cast<const float4*>(
                ft + (size_t)v * FT_ROW + (size_t)cg * 4);
            #pragma unroll
            for (int k = 0; k < RTOT; ++k) {
                float4 t = p[k * C4];   // stride 300 floats between rows
                sx += t.x; sy += t.y; sz += t.z; sw += t.w;
            }
        }
        reinterpret_cast<float4*>(lds)[i] = make_float4(sx, sy, sz, sw);
    }
    __syncthreads();

    // ---- phase 2: [16 x 300] @ W^T -> [16 x 100] ----
    const int wave = tid >> 6;
    const int lane = tid & 63;
    const int r0 = wave * 4;
    const int o0 = lane;                       // 0..63, always valid (<100)
    const int o1 = lane + 64;                  // 64..127, valid if <100
    const int o1c = (o1 < OUTC) ? o1 : (OUTC - 1);

    float acc0[4] = {0.f, 0.f, 0.f, 0.f};
    float acc1[4] = {0.f, 0.f, 0.f, 0.f};
    const float4* W0 = reinterpret_cast<const float4*>(W + (size_t)o0  * GLOVE);
    const float4* W1 = reinterpret_cast<const float4*>(W + (size_t)o1c * GLOVE);
    const float4* L4 = reinterpret_cast<const float4*>(lds);

    for (int c = 0; c < C4; ++c) {
        const float4 w0 = W0[c];
        const float4 w1 = W1[c];
        #pragma unroll
        for (int i = 0; i < 4; ++i) {
            const float4 s = L4[(r0 + i) * C4 + c];  // wave-uniform broadcast
            acc0[i] += s.x * w0.x + s.y * w0.y + s.z * w0.z + s.w * w0.w;
            acc1[i] += s.x * w1.x + s.y * w1.y + s.z * w1.z + s.w * w1.w;
        }
    }
    #pragma unroll
    for (int i = 0; i < 4; ++i) {
        const size_t v = (size_t)(vbase + r0 + i);
        proj[v * OUTC + o0] = acc0[i];
        if (o1 < OUTC) proj[v * OUTC + o1] = acc1[i];
    }
}

// ---------------------------------------------------------------------------
// K3: out[n][o] = (1/128) * sum_j proj[label[n][j]][o] + bias[o]
// Thread per (n,o); consecutive idx -> consecutive o -> coalesced reads/writes.
// proj (8 MB) is L2/L3-hot right after K2.
// ---------------------------------------------------------------------------
__global__ __launch_bounds__(256) void k_gather(const int* __restrict__ labels,
                                                const float* __restrict__ proj,
                                                const float* __restrict__ bias,
                                                float* __restrict__ out) {
    const int idx = blockIdx.x * 256 + threadIdx.x;
    if (idx >= NOUT * OUTC) return;
    const int n = idx / OUTC;
    const int o = idx - n * OUTC;
    const int* lab = labels + n * NLAB;
    float s = 0.f;
    #pragma unroll
    for (int j = 0; j < NLAB; ++j) {
        s += proj[(size_t)lab[j] * OUTC + o];
    }
    out[idx] = s * (1.0f / 128.0f) + bias[o];
}

// ---------------------------------------------------------------------------
// Fallback (only if ws too small): direct gather+reduce+conv per (b,l).
// ---------------------------------------------------------------------------
__global__ __launch_bounds__(128) void k_direct(const int* __restrict__ labels,
                                                const float* __restrict__ ft,
                                                const float* __restrict__ W,
                                                const float* __restrict__ bias,
                                                float* __restrict__ out) {
    __shared__ float4 sv[C4];
    const int n = blockIdx.x;
    const int tid = threadIdx.x;
    if (tid < C4) {
        float sx = 0.f, sy = 0.f, sz = 0.f, sw = 0.f;
        for (int j = 0; j < NLAB; ++j) {
            const int v = labels[n * NLAB + j];
            const float4* p = reinterpret_cast<const float4*>(
                ft + (size_t)v * FT_ROW + (size_t)tid * 4);
            #pragma unroll
            for (int k = 0; k < RTOT; ++k) {
                float4 t = p[k * C4];
                sx += t.x; sy += t.y; sz += t.z; sw += t.w;
            }
        }
        sv[tid] = make_float4(sx, sy, sz, sw);
    }
    __syncthreads();
    if (tid < OUTC) {
        const float4* w4 = reinterpret_cast<const float4*>(W + (size_t)tid * GLOVE);
        float a = 0.f;
        for (int c = 0; c < C4; ++c) {
            const float4 w = w4[c];
            const float4 s = sv[c];
            a += s.x * w.x + s.y * w.y + s.z * w.z + s.w * w.w;
        }
        out[(size_t)n * OUTC + tid] = a * (1.0f / 128.0f) + bias[tid];
    }
}

extern "C" void kernel_launch(void* const* d_in, const int* in_sizes, int n_in,
                              void* d_out, int out_size, void* d_ws, size_t ws_size,
                              hipStream_t stream) {
    const int*   labels = (const int*)d_in[0];    // [32,128,8] int32
    const float* ft     = (const float*)d_in[1];  // [20000,8,600] f32
    const float* W      = (const float*)d_in[2];  // [100,300] f32
    const float* bias   = (const float*)d_in[3];  // [100] f32
    float* out = (float*)d_out;                   // [32,128,100] f32

    const size_t flags_bytes = (size_t)VOCAB * sizeof(int);          // 80 KB
    const size_t proj_bytes  = (size_t)VOCAB * OUTC * sizeof(float); // 8 MB

    if (ws_size >= flags_bytes + proj_bytes) {
        int*   flags = (int*)d_ws;
        float* proj  = (float*)((char*)d_ws + flags_bytes);
        hipMemsetAsync(flags, 0, flags_bytes, stream);
        const int nlabels = NOUT * NLAB; // 32768
        k_flags<<<(nlabels + 255) / 256, 256, 0, stream>>>(labels, flags, nlabels);
        k_reduce_proj<<<VOCAB / ROWS_A, 256, 0, stream>>>(ft, W, flags, proj);
        k_gather<<<(NOUT * OUTC + 255) / 256, 256, 0, stream>>>(labels, proj, bias, out);
    } else {
        k_direct<<<NOUT, 128, 0, stream>>>(labels, ft, W, bias, out);
    }
}

// Round 2
// 503.944 us; speedup vs baseline: 1.1301x; 1.1301x over previous
//
#include <hip/hip_runtime.h>

// Problem constants (from reference)
#define VOCAB   20000
#define GLOVE   300
#define C4      75            // GLOVE/4 float4 groups per 300-col row
#define RTOT    16            // 2*TOP_K rows of 300 per vocab entry
#define OUTC    100
#define NLAB    8
#define NOUT    4096          // B*L
#define FT_ROW  (RTOT * GLOVE)   // 4800 floats per vocab entry
#define ROWS_A  16            // vocab rows per block in reduce kernel
#define NITEM   (ROWS_A * C4) // 1200 work items per block

typedef float v4f __attribute__((ext_vector_type(4)));

// ---------------------------------------------------------------------------
// K1: scatter flags — mark which vocab rows are referenced by any label.
// ---------------------------------------------------------------------------
__global__ __launch_bounds__(256) void k_flags(const int* __restrict__ labels,
                                               int* __restrict__ flags, int n) {
    int i = blockIdx.x * 256 + threadIdx.x;
    if (i < n) flags[labels[i]] = 1;
}

// ---------------------------------------------------------------------------
// K1b: transpose W[100][300] into grouped form Wtg[75][100] of float4:
//   Wtg[g*100+o] = {W[o][4g], W[o][4g+1], W[o][4g+2], W[o][4g+3]}
// This makes phase-2 weight loads lane-coalesced (consecutive o per lane).
// ---------------------------------------------------------------------------
__global__ __launch_bounds__(256) void k_wt(const float4* __restrict__ W4,
                                            float4* __restrict__ Wtg) {
    int i = blockIdx.x * 256 + threadIdx.x;   // over 75*100
    if (i < C4 * OUTC) {
        int g = i / OUTC, o = i - g * OUTC;
        Wtg[i] = W4[(size_t)o * C4 + g];
    }
}

// ---------------------------------------------------------------------------
// K2 (the big one): for each touched vocab row v:
//   rowsum[c] = sum_{r<16} ft[v][r*300 + c]          (phase 1, LDS)
//   proj[v][o] = sum_c rowsum[c] * W[o][c]           (phase 2)
// Block = 256 threads, 16 vocab rows. LDS = 19.2 KB -> 8 blocks/CU possible.
// Phase 1: streaming float4 nontemporal loads, flag-skipped.
// Phase 2: wave w owns rows 4w..4w+3; lane -> outputs (lane, lane+64);
//   rowsum via wave-uniform ds_read_b128 broadcast; weights via coalesced
//   Wtg float4 loads (shared across the wave's 4 rows).
// ---------------------------------------------------------------------------
__global__ __launch_bounds__(256) void k_reduce_proj(const float* __restrict__ ft,
                                                     const float4* __restrict__ Wtg,
                                                     const int* __restrict__ flags,
                                                     float* __restrict__ proj) {
    __shared__ float lds[ROWS_A * GLOVE];
    const int vbase = blockIdx.x * ROWS_A;
    const int tid = threadIdx.x;

    // ---- phase 1: global -> LDS rowsum, coalesced float4, flag-skipped ----
    for (int i = tid; i < NITEM; i += 256) {
        const int r  = i / C4;         // local vocab row 0..15
        const int cg = i - r * C4;     // float4 column group 0..74
        const int v  = vbase + r;
        v4f s = {0.f, 0.f, 0.f, 0.f};
        if (flags[v]) {
            const v4f* p = reinterpret_cast<const v4f*>(
                ft + (size_t)v * FT_ROW + (size_t)cg * 4);
            #pragma unroll
            for (int k = 0; k < RTOT; ++k) {
                v4f t = __builtin_nontemporal_load(p + k * C4); // stride 300 floats
                s += t;
            }
        }
        reinterpret_cast<v4f*>(lds)[i] = s;
    }
    __syncthreads();

    // ---- phase 2: [16 x 300] @ Wt -> [16 x 100] ----
    const int wave = tid >> 6;
    const int lane = tid & 63;
    const int r0 = wave * 4;
    const int o0 = lane;                       // 0..63, always valid (<100)
    const int o1 = lane + 64;                  // 64..127, valid if <100
    const int o1c = (o1 < OUTC) ? o1 : (OUTC - 1);

    float acc0[4] = {0.f, 0.f, 0.f, 0.f};
    float acc1[4] = {0.f, 0.f, 0.f, 0.f};
    const v4f* L4 = reinterpret_cast<const v4f*>(lds);

    for (int g = 0; g < C4; ++g) {
        const float4 w0 = Wtg[g * OUTC + o0];   // coalesced across lanes
        const float4 w1 = Wtg[g * OUTC + o1c];
        #pragma unroll
        for (int i = 0; i < 4; ++i) {
            const v4f s = L4[(r0 + i) * C4 + g];  // wave-uniform broadcast
            acc0[i] += s.x * w0.x + s.y * w0.y + s.z * w0.z + s.w * w0.w;
            acc1[i] += s.x * w1.x + s.y * w1.y + s.z * w1.z + s.w * w1.w;
        }
    }
    #pragma unroll
    for (int i = 0; i < 4; ++i) {
        const size_t v = (size_t)(vbase + r0 + i);
        proj[v * OUTC + o0] = acc0[i];
        if (o1 < OUTC) proj[v * OUTC + o1] = acc1[i];
    }
}

// ---------------------------------------------------------------------------
// K3: out[n][o] = (1/128) * sum_j proj[label[n][j]][o] + bias[o]
// float2-vectorized: thread per (n, o/2). proj is L2/L3-hot right after K2.
// ---------------------------------------------------------------------------
#define OUT2 (OUTC / 2)
__global__ __launch_bounds__(256) void k_gather(const int* __restrict__ labels,
                                                const float2* __restrict__ proj2,
                                                const float2* __restrict__ bias2,
                                                float2* __restrict__ out2) {
    const int idx = blockIdx.x * 256 + threadIdx.x;
    if (idx >= NOUT * OUT2) return;
    const int n = idx / OUT2;
    const int o = idx - n * OUT2;
    const int* lab = labels + n * NLAB;
    float sx = 0.f, sy = 0.f;
    #pragma unroll
    for (int j = 0; j < NLAB; ++j) {
        const float2 p = proj2[(size_t)lab[j] * OUT2 + o];
        sx += p.x; sy += p.y;
    }
    const float2 b = bias2[o];
    out2[idx] = make_float2(sx * (1.0f / 128.0f) + b.x,
                            sy * (1.0f / 128.0f) + b.y);
}

// ---------------------------------------------------------------------------
// Fallback (only if ws too small): direct gather+reduce+conv per (b,l).
// ---------------------------------------------------------------------------
__global__ __launch_bounds__(128) void k_direct(const int* __restrict__ labels,
                                                const float* __restrict__ ft,
                                                const float* __restrict__ W,
                                                const float* __restrict__ bias,
                                                float* __restrict__ out) {
    __shared__ float4 sv[C4];
    const int n = blockIdx.x;
    const int tid = threadIdx.x;
    if (tid < C4) {
        float sx = 0.f, sy = 0.f, sz = 0.f, sw = 0.f;
        for (int j = 0; j < NLAB; ++j) {
            const int v = labels[n * NLAB + j];
            const float4* p = reinterpret_cast<const float4*>(
                ft + (size_t)v * FT_ROW + (size_t)tid * 4);
            #pragma unroll
            for (int k = 0; k < RTOT; ++k) {
                float4 t = p[k * C4];
                sx += t.x; sy += t.y; sz += t.z; sw += t.w;
            }
        }
        sv[tid] = make_float4(sx, sy, sz, sw);
    }
    __syncthreads();
    if (tid < OUTC) {
        const float4* w4 = reinterpret_cast<const float4*>(W + (size_t)tid * GLOVE);
        float a = 0.f;
        for (int c = 0; c < C4; ++c) {
            const float4 w = w4[c];
            const float4 s = sv[c];
            a += s.x * w.x + s.y * w.y + s.z * w.z + s.w * w.w;
        }
        out[(size_t)n * OUTC + tid] = a * (1.0f / 128.0f) + bias[tid];
    }
}

extern "C" void kernel_launch(void* const* d_in, const int* in_sizes, int n_in,
                              void* d_out, int out_size, void* d_ws, size_t ws_size,
                              hipStream_t stream) {
    const int*   labels = (const int*)d_in[0];    // [32,128,8] int32
    const float* ft     = (const float*)d_in[1];  // [20000,8,600] f32
    const float* W      = (const float*)d_in[2];  // [100,300] f32
    const float* bias   = (const float*)d_in[3];  // [100] f32
    float* out = (float*)d_out;                   // [32,128,100] f32

    const size_t flags_bytes = (size_t)VOCAB * sizeof(int);            // 80 KB
    const size_t wt_bytes    = (size_t)C4 * OUTC * sizeof(float4);     // 120 KB
    const size_t proj_bytes  = (size_t)VOCAB * OUTC * sizeof(float);   // 8 MB

    if (ws_size >= flags_bytes + wt_bytes + proj_bytes) {
        int*    flags = (int*)d_ws;
        float4* Wtg   = (float4*)((char*)d_ws + flags_bytes);
        float*  proj  = (float*)((char*)d_ws + flags_bytes + wt_bytes);

        hipMemsetAsync(flags, 0, flags_bytes, stream);
        const int nlabels = NOUT * NLAB; // 32768
        k_flags<<<(nlabels + 255) / 256, 256, 0, stream>>>(labels, flags, nlabels);
        k_wt<<<(C4 * OUTC + 255) / 256, 256, 0, stream>>>((const float4*)W, Wtg);
        k_reduce_proj<<<VOCAB / ROWS_A, 256, 0, stream>>>(ft, Wtg, flags, proj);
        k_gather<<<(NOUT * OUT2 + 255) / 256, 256, 0, stream>>>(
            labels, (const float2*)proj, (const float2*)bias, (float2*)out);
    } else {
        k_direct<<<NOUT, 128, 0, stream>>>(labels, ft, W, bias, out);
    }
}

// Round 3
// 502.040 us; speedup vs baseline: 1.1344x; 1.0038x over previous
//
#include <hip/hip_runtime.h>

// Problem constants (from reference)
#define VOCAB   20000
#define GLOVE   300
#define C4      75            // GLOVE/4 float4 groups per 300-col row
#define RTOT    16            // 2*TOP_K rows of 300 per vocab entry
#define OUTC    100
#define NLAB    8
#define NOUT    4096          // B*L
#define FT_ROW  (RTOT * GLOVE)   // 4800 floats per vocab entry
#define ROWS_A  16            // vocab rows per block in reduce kernel
#define NITEM   (ROWS_A * C4) // 1200 work items per block

typedef float v4f __attribute__((ext_vector_type(4)));

// ---------------------------------------------------------------------------
// K1: scatter flags — mark which vocab rows are referenced by any label.
// ---------------------------------------------------------------------------
__global__ __launch_bounds__(256) void k_flags(const int* __restrict__ labels,
                                               int* __restrict__ flags, int n) {
    int i = blockIdx.x * 256 + threadIdx.x;
    if (i < n) flags[labels[i]] = 1;
}

// ---------------------------------------------------------------------------
// K2: stream-compact touched vocab rows into list[] (order irrelevant),
//     and (fused) transpose W[100][300] -> Wtg[75][100] float4 groups:
//     Wtg[g*100+o] = {W[o][4g..4g+3]}  (lane-coalesced weight loads later).
// One atomic per wave (ballot-aggregated).
// ---------------------------------------------------------------------------
__global__ __launch_bounds__(256) void k_compact_wt(const int* __restrict__ flags,
                                                    int* __restrict__ list,
                                                    int* __restrict__ count,
                                                    const float4* __restrict__ W4,
                                                    float4* __restrict__ Wtg) {
    const int i = blockIdx.x * 256 + threadIdx.x;
    const int lane = threadIdx.x & 63;
    const bool on = (i < VOCAB) && (flags[i] != 0);
    const unsigned long long m = __ballot(on);
    int base = 0;
    if (lane == 0 && m) base = atomicAdd(count, (int)__popcll(m));
    base = __shfl(base, 0);
    if (on) {
        const int off = (int)__popcll(m & ((1ull << lane) - 1ull));
        list[base + off] = i;
    }
    if (i < C4 * OUTC) {
        const int g = i / OUTC, o = i - g * OUTC;
        Wtg[i] = W4[(size_t)o * C4 + g];
    }
}

// ---------------------------------------------------------------------------
// K3 (the big one): for each touched vocab row v = list[...]:
//   rowsum[c] = sum_{r<16} ft[v][r*300 + c]          (phase 1, LDS)
//   proj[v][o] = sum_c rowsum[c] * W[o][c]           (phase 2)
// Block = 256 threads, 16 list entries. LDS = 19.2 KB.
// Tail entries duplicate list[count-1] -> duplicate identical proj writes
// (benign race, bit-identical values).
// ---------------------------------------------------------------------------
__global__ __launch_bounds__(256) void k_reduce_proj(const float* __restrict__ ft,
                                                     const float4* __restrict__ Wtg,
                                                     const int* __restrict__ list,
                                                     const int* __restrict__ count,
                                                     float* __restrict__ proj) {
    __shared__ float lds[ROWS_A * GLOVE];
    __shared__ int svrows[ROWS_A];
    const int cnt = *count;
    const int lbase = blockIdx.x * ROWS_A;
    if (lbase >= cnt) return;
    const int tid = threadIdx.x;

    if (tid < ROWS_A) {
        const int idx = lbase + tid;
        svrows[tid] = list[(idx < cnt) ? idx : (cnt - 1)];
    }
    __syncthreads();

    // ---- phase 1: global -> LDS rowsum, coalesced float4 ----
    for (int i = tid; i < NITEM; i += 256) {
        const int r  = i / C4;         // local row slot 0..15
        const int cg = i - r * C4;     // float4 column group 0..74
        const int v  = svrows[r];
        const v4f* p = reinterpret_cast<const v4f*>(
            ft + (size_t)v * FT_ROW + (size_t)cg * 4);
        v4f s = {0.f, 0.f, 0.f, 0.f};
        #pragma unroll
        for (int k = 0; k < RTOT; ++k) {
            s += __builtin_nontemporal_load(p + k * C4);  // stride 300 floats
        }
        reinterpret_cast<v4f*>(lds)[i] = s;
    }
    __syncthreads();

    // ---- phase 2: [16 x 300] @ Wt -> [16 x 100] ----
    const int wave = tid >> 6;
    const int lane = tid & 63;
    const int r0 = wave * 4;
    const int o0 = lane;                       // 0..63, always valid (<100)
    const int o1 = lane + 64;                  // 64..127, valid if <100
    const int o1c = (o1 < OUTC) ? o1 : (OUTC - 1);

    float acc0[4] = {0.f, 0.f, 0.f, 0.f};
    float acc1[4] = {0.f, 0.f, 0.f, 0.f};
    const v4f* L4 = reinterpret_cast<const v4f*>(lds);

    for (int g = 0; g < C4; ++g) {
        const float4 w0 = Wtg[g * OUTC + o0];   // coalesced across lanes
        const float4 w1 = Wtg[g * OUTC + o1c];
        #pragma unroll
        for (int i = 0; i < 4; ++i) {
            const v4f s = L4[(r0 + i) * C4 + g];  // wave-uniform broadcast
            acc0[i] += s.x * w0.x + s.y * w0.y + s.z * w0.z + s.w * w0.w;
            acc1[i] += s.x * w1.x + s.y * w1.y + s.z * w1.z + s.w * w1.w;
        }
    }
    #pragma unroll
    for (int i = 0; i < 4; ++i) {
        const size_t v = (size_t)svrows[r0 + i];
        proj[v * OUTC + o0] = acc0[i];
        if (o1 < OUTC) proj[v * OUTC + o1] = acc1[i];
    }
}

// ---------------------------------------------------------------------------
// K4: out[n][o] = (1/128) * sum_j proj[label[n][j]][o] + bias[o]
// float2-vectorized: thread per (n, o/2). proj is L2/L3-hot right after K3.
// ---------------------------------------------------------------------------
#define OUT2 (OUTC / 2)
__global__ __launch_bounds__(256) void k_gather(const int* __restrict__ labels,
                                                const float2* __restrict__ proj2,
                                                const float2* __restrict__ bias2,
                                                float2* __restrict__ out2) {
    const int idx = blockIdx.x * 256 + threadIdx.x;
    if (idx >= NOUT * OUT2) return;
    const int n = idx / OUT2;
    const int o = idx - n * OUT2;
    const int* lab = labels + n * NLAB;
    float sx = 0.f, sy = 0.f;
    #pragma unroll
    for (int j = 0; j < NLAB; ++j) {
        const float2 p = proj2[(size_t)lab[j] * OUT2 + o];
        sx += p.x; sy += p.y;
    }
    const float2 b = bias2[o];
    out2[idx] = make_float2(sx * (1.0f / 128.0f) + b.x,
                            sy * (1.0f / 128.0f) + b.y);
}

// ---------------------------------------------------------------------------
// Fallback (only if ws too small): direct gather+reduce+conv per (b,l).
// ---------------------------------------------------------------------------
__global__ __launch_bounds__(128) void k_direct(const int* __restrict__ labels,
                                                const float* __restrict__ ft,
                                                const float* __restrict__ W,
                                                const float* __restrict__ bias,
                                                float* __restrict__ out) {
    __shared__ float4 sv[C4];
    const int n = blockIdx.x;
    const int tid = threadIdx.x;
    if (tid < C4) {
        float sx = 0.f, sy = 0.f, sz = 0.f, sw = 0.f;
        for (int j = 0; j < NLAB; ++j) {
            const int v = labels[n * NLAB + j];
            const float4* p = reinterpret_cast<const float4*>(
                ft + (size_t)v * FT_ROW + (size_t)tid * 4);
            #pragma unroll
            for (int k = 0; k < RTOT; ++k) {
                float4 t = p[k * C4];
                sx += t.x; sy += t.y; sz += t.z; sw += t.w;
            }
        }
        sv[tid] = make_float4(sx, sy, sz, sw);
    }
    __syncthreads();
    if (tid < OUTC) {
        const float4* w4 = reinterpret_cast<const float4*>(W + (size_t)tid * GLOVE);
        float a = 0.f;
        for (int c = 0; c < C4; ++c) {
            const float4 w = w4[c];
            const float4 s = sv[c];
            a += s.x * w.x + s.y * w.y + s.z * w.z + s.w * w.w;
        }
        out[(size_t)n * OUTC + tid] = a * (1.0f / 128.0f) + bias[tid];
    }
}

extern "C" void kernel_launch(void* const* d_in, const int* in_sizes, int n_in,
                              void* d_out, int out_size, void* d_ws, size_t ws_size,
                              hipStream_t stream) {
    const int*   labels = (const int*)d_in[0];    // [32,128,8] int32
    const float* ft     = (const float*)d_in[1];  // [20000,8,600] f32
    const float* W      = (const float*)d_in[2];  // [100,300] f32
    const float* bias   = (const float*)d_in[3];  // [100] f32
    float* out = (float*)d_out;                   // [32,128,100] f32

    // ws layout: [flags 80KB][count 16B][list 80KB][Wtg 120KB][proj 8MB]
    const size_t flags_bytes = (size_t)VOCAB * sizeof(int);
    const size_t count_bytes = 16;
    const size_t list_bytes  = (size_t)VOCAB * sizeof(int);
    const size_t wt_bytes    = (size_t)C4 * OUTC * sizeof(float4);
    const size_t proj_bytes  = (size_t)VOCAB * OUTC * sizeof(float);

    if (ws_size >= flags_bytes + count_bytes + list_bytes + wt_bytes + proj_bytes) {
        char* w = (char*)d_ws;
        int*    flags = (int*)w;                      w += flags_bytes;
        int*    count = (int*)w;                      w += count_bytes;
        int*    list  = (int*)w;                      w += list_bytes;
        float4* Wtg   = (float4*)w;                   w += wt_bytes;
        float*  proj  = (float*)w;

        hipMemsetAsync(flags, 0, flags_bytes + count_bytes, stream);
        const int nlabels = NOUT * NLAB; // 32768
        k_flags<<<(nlabels + 255) / 256, 256, 0, stream>>>(labels, flags, nlabels);
        k_compact_wt<<<(VOCAB + 255) / 256, 256, 0, stream>>>(
            flags, list, count, (const float4*)W, Wtg);
        k_reduce_proj<<<(VOCAB + ROWS_A - 1) / ROWS_A, 256, 0, stream>>>(
            ft, Wtg, list, count, proj);
        k_gather<<<(NOUT * OUT2 + 255) / 256, 256, 0, stream>>>(
            labels, (const float2*)proj, (const float2*)bias, (float2*)out);
    } else {
        k_direct<<<NOUT, 128, 0, stream>>>(labels, ft, W, bias, out);
    }
}